// Round 3
// baseline (344.414 us; speedup 1.0000x reference)
//
#include <hip/hip_runtime.h>
#include <hip/hip_bf16.h>
#include <hip/hip_fp16.h>

typedef __bf16 bf16x8 __attribute__((ext_vector_type(8)));
typedef float  f32x4  __attribute__((ext_vector_type(4)));

#define C_H 56
#define C_W 56
#define C_C 256
#define C_F 256
#define C_B 64
#define N_PIX (C_B * C_H * C_W)          // 200704
#define WB_ELEMS (9 * C_C * C_F)         // 589824
#define WB_BYTES (WB_ELEMS * 2)          // 1179648
#define ZBUF_BYTES 1024
#define XB_OFF (WB_BYTES + ZBUF_BYTES)   // 1180672 (16B aligned)
#define X_ELEMS (N_PIX * C_C)            // 51380224

#define GLOAD_LDS16(g, l)                                                   \
    __builtin_amdgcn_global_load_lds(                                        \
        (const __attribute__((address_space(1))) void*)(g),                  \
        (__attribute__((address_space(3))) void*)(l), 16, 0, 0)

// ---- prep: binarize + transpose weights: w[s][c][f] fp32 -> wbT[s][f][c] bf16 ----
__global__ void prep_w_kernel(const float* __restrict__ w, __bf16* __restrict__ wbT) {
    int idx = blockIdx.x * 256 + threadIdx.x;       // 589824 total
    int f = idx & 255;
    int c = (idx >> 8) & 255;
    int s = idx >> 16;
    float wf = w[idx];
    float v = __half2float(__float2half(wf));       // fp16 round-trip
    float sgn = (v > 0.f) ? 1.f : ((v < 0.f) ? -1.f : 0.f);
    wbT[(s << 16) + (f << 8) + c] = (__bf16)sgn;
}

__global__ void zero_kernel(float* __restrict__ z) {
    z[threadIdx.x] = 0.f;   // 1KB zero page
}

__global__ void prep_x_kernel(const float* __restrict__ x, __bf16* __restrict__ xb) {
    int i = blockIdx.x * 256 + threadIdx.x;
    const f32x4* p = reinterpret_cast<const f32x4*>(x) + (size_t)i * 2;
    f32x4 a = p[0], b = p[1];
    bf16x8 o;
    o[0] = (__bf16)a[0]; o[1] = (__bf16)a[1]; o[2] = (__bf16)a[2]; o[3] = (__bf16)a[3];
    o[4] = (__bf16)b[0]; o[5] = (__bf16)b[1]; o[6] = (__bf16)b[2]; o[7] = (__bf16)b[3];
    reinterpret_cast<bf16x8*>(xb)[i] = o;
}

// ---- main conv: 256x256 tile, 8 waves, BK=32, 4-deep counted-vmcnt pipeline ----
// K order cc-major: kt = cc*9 + s  (s fastest -> shifted x re-reads are L2-hot)
// LDS: 4 bufs x (A 16KB + B 16KB) = 128KB. stage kt t+3 while computing kt t.
// swizzle: byte_col ^= (row&3)<<4 on 64B rows (both-sides: source + read).
__global__ __launch_bounds__(512, 2) void conv_mfma8_kernel(
    const char* __restrict__ xbp,      // bf16 x [pixel][256c], 512B rows
    const char* __restrict__ wbp,      // bf16 wbT[s][f][c], 512B rows
    const char* __restrict__ zp,       // >=64B zeros, 16B aligned
    float* __restrict__ out) {

    __shared__ __align__(16) char sm[4][32768];   // [buf][A 16KB | B 16KB]

    // XCD-aware chunked swizzle: 784 blocks = 8 XCDs x 98
    const int nbid = (blockIdx.x & 7) * 98 + (blockIdx.x >> 3);
    const long m0 = (long)nbid * 256;

    const int tid  = threadIdx.x;
    const int lane = tid & 63;
    const int wave = tid >> 6;          // 0..7
    const int l15  = lane & 15;
    const int g4   = lane >> 4;         // 0..3
    const int wm   = wave >> 2;         // 0..1  (M half)
    const int wn   = wave & 3;          // 0..3  (N quarter)
    const int colr = ((g4 ^ (l15 & 3)) << 4);   // swizzled read col within 64B row

    // ---- staging precompute: thread covers rows r0 and r0+128, col (tid&3)*16 ----
    const int r0 = tid >> 2;                       // 0..127
    const int sw = (((tid & 3) << 4)) ^ ((r0 & 3) << 4);   // inverse-swizzled src col
    const int p0 = (int)m0 + r0;
    const int p1 = p0 + 128;
    const int rem0 = p0 % 3136;
    const int rem1 = p1 % 3136;
    const int y0 = rem0 / 56, x0 = rem0 - (rem0 / 56) * 56;
    const int y1 = rem1 / 56, x1 = rem1 - (rem1 / 56) * 56;

    auto stage = [&](int kts) {
        int cc = (kts * 57) >> 9;            // kts/9 for kts<72
        int s  = kts - 9 * cc;
        int s3 = (s * 171) >> 9;             // s/3
        int dy = s3 - 1;
        int dx = s - 3 * s3 - 1;
        int doff = dy * 56 + dx;
        size_t cb = (size_t)(cc << 6) + sw;
        bool v0 = ((unsigned)(y0 + dy) < 56u) & ((unsigned)(x0 + dx) < 56u);
        bool v1 = ((unsigned)(y1 + dy) < 56u) & ((unsigned)(x1 + dx) < 56u);
        const char* a0 = v0 ? xbp + (size_t)(p0 + doff) * 512 + cb : zp + sw;
        const char* a1 = v1 ? xbp + (size_t)(p1 + doff) * 512 + cb : zp + sw;
        const char* b0 = wbp + (size_t)((s << 8) + r0) * 512 + cb;
        const char* b1 = wbp + (size_t)((s << 8) + r0 + 128) * 512 + cb;
        char* L = &sm[kts & 3][0];
        GLOAD_LDS16(a0, L + tid * 16);
        GLOAD_LDS16(a1, L + 8192 + tid * 16);
        GLOAD_LDS16(b0, L + 16384 + tid * 16);
        GLOAD_LDS16(b1, L + 24576 + tid * 16);
    };

    f32x4 acc[8][4];
#pragma unroll
    for (int i = 0; i < 8; ++i)
#pragma unroll
        for (int j = 0; j < 4; ++j)
            acc[i][j] = (f32x4){0.f, 0.f, 0.f, 0.f};

    auto body = [&](int t, bool do_stage) {
        const char* L = &sm[t & 3][0];
        const char* Ab = L + (size_t)(wm * 128 + l15) * 64 + colr;
        const char* Bb = L + 16384 + (size_t)(wn * 64 + l15) * 64 + colr;
        bf16x8 Af[8], Bf[4];
#pragma unroll
        for (int ai = 0; ai < 8; ++ai)
            Af[ai] = *reinterpret_cast<const bf16x8*>(Ab + ai * 1024);
#pragma unroll
        for (int bj = 0; bj < 4; ++bj)
            Bf[bj] = *reinterpret_cast<const bf16x8*>(Bb + bj * 1024);
        if (do_stage) stage(t + 3);
        __builtin_amdgcn_s_setprio(1);
#pragma unroll
        for (int ai = 0; ai < 8; ++ai)
#pragma unroll
            for (int bj = 0; bj < 4; ++bj)
                acc[ai][bj] = __builtin_amdgcn_mfma_f32_16x16x32_bf16(
                    Af[ai], Bf[bj], acc[ai][bj], 0, 0, 0);
        __builtin_amdgcn_s_setprio(0);
    };

    // ---- prologue: 3 K-tiles in flight ----
    stage(0); stage(1); stage(2);

    // ---- main loop: counted vmcnt(8) = 2 K-tiles outstanding, never drain ----
    for (int t = 0; t < 69; ++t) {
        asm volatile("s_waitcnt vmcnt(8)" ::: "memory");
        __builtin_amdgcn_s_barrier();
        __builtin_amdgcn_sched_barrier(0);
        body(t, true);
    }
    asm volatile("s_waitcnt vmcnt(8)" ::: "memory");
    __builtin_amdgcn_s_barrier();
    __builtin_amdgcn_sched_barrier(0);
    body(69, false);
    asm volatile("s_waitcnt vmcnt(4)" ::: "memory");
    __builtin_amdgcn_s_barrier();
    __builtin_amdgcn_sched_barrier(0);
    body(70, false);
    asm volatile("s_waitcnt vmcnt(0)" ::: "memory");
    __builtin_amdgcn_s_barrier();
    __builtin_amdgcn_sched_barrier(0);
    body(71, false);

    // ---- epilogue: D col(f)=lane&15, row(pixel)=(lane>>4)*4+j ----
#pragma unroll
    for (int ai = 0; ai < 8; ++ai) {
#pragma unroll
        for (int j = 0; j < 4; ++j) {
            long row = m0 + wm * 128 + ai * 16 + g4 * 4 + j;
            float* op = out + row * C_F + wn * 64 + l15;
#pragma unroll
            for (int bj = 0; bj < 4; ++bj)
                op[bj * 16] = acc[ai][bj][j];
        }
    }
}

// ---- fallback (small ws): direct-from-global version ----
__global__ __launch_bounds__(256) void conv_fallback_kernel(
    const float* __restrict__ xf,
    const __bf16* __restrict__ wbT, const char* __restrict__ zbuf,
    float* __restrict__ out) {

    const int lane = threadIdx.x & 63;
    const int wave = threadIdx.x >> 6;
    const int l15  = lane & 15;
    const int g    = lane >> 4;
    const int goff = g * 8;
    const long m0  = (long)blockIdx.x * 64;
    const int fbase = wave * 64;

    int ry[4], rx[4];
    long rbase[4];
#pragma unroll
    for (int ai = 0; ai < 4; ++ai) {
        int rr = (int)m0 + ai * 16 + l15;
        int b = rr / 3136;
        int rem = rr - b * 3136;
        int yy2 = rem / 56;
        ry[ai] = yy2;
        rx[ai] = rem - yy2 * 56;
        rbase[ai] = (long)rr * C_C;
    }

    f32x4 acc[4][4];
#pragma unroll
    for (int i = 0; i < 4; ++i)
#pragma unroll
        for (int j = 0; j < 4; ++j)
            acc[i][j] = (f32x4){0.f, 0.f, 0.f, 0.f};

    for (int s = 0; s < 9; ++s) {
        const int dy = s / 3 - 1;
        const int dx = (s - (s / 3) * 3) - 1;
        const float* af[4];
#pragma unroll
        for (int ai = 0; ai < 4; ++ai) {
            bool v = ((unsigned)(ry[ai] + dy) < 56u) & ((unsigned)(rx[ai] + dx) < 56u);
            long off = rbase[ai] + (long)(dy * C_W + dx) * C_C + goff;
            af[ai] = v ? (xf + off) : ((const float*)zbuf + goff);
        }
        const __bf16* bp = wbT + ((size_t)(s * 256 + fbase + l15)) * C_C + goff;

#pragma unroll
        for (int cc = 0; cc < 8; ++cc) {
            const int c0 = cc * 32;
            bf16x8 A[4], Bf[4];
#pragma unroll
            for (int ai = 0; ai < 4; ++ai) {
                const f32x4* p = reinterpret_cast<const f32x4*>(af[ai] + c0);
                f32x4 u = p[0], w2 = p[1];
                bf16x8 t;
                t[0] = (__bf16)u[0]; t[1] = (__bf16)u[1]; t[2] = (__bf16)u[2]; t[3] = (__bf16)u[3];
                t[4] = (__bf16)w2[0]; t[5] = (__bf16)w2[1]; t[6] = (__bf16)w2[2]; t[7] = (__bf16)w2[3];
                A[ai] = t;
            }
#pragma unroll
            for (int bj = 0; bj < 4; ++bj)
                Bf[bj] = *reinterpret_cast<const bf16x8*>(bp + bj * 16 * C_C + c0);
#pragma unroll
            for (int ai = 0; ai < 4; ++ai)
#pragma unroll
                for (int bj = 0; bj < 4; ++bj)
                    acc[ai][bj] = __builtin_amdgcn_mfma_f32_16x16x32_bf16(A[ai], Bf[bj], acc[ai][bj], 0, 0, 0);
        }
    }

#pragma unroll
    for (int ai = 0; ai < 4; ++ai) {
#pragma unroll
        for (int j = 0; j < 4; ++j) {
            long row = m0 + ai * 16 + g * 4 + j;
            float* op = out + row * C_F + fbase + l15;
#pragma unroll
            for (int bj = 0; bj < 4; ++bj)
                op[bj * 16] = acc[ai][bj][j];
        }
    }
}

extern "C" void kernel_launch(void* const* d_in, const int* in_sizes, int n_in,
                              void* d_out, int out_size, void* d_ws, size_t ws_size,
                              hipStream_t stream) {
    const float* x = (const float*)d_in[0];
    const float* w = (const float*)d_in[1];
    float* out = (float*)d_out;

    char* ws = (char*)d_ws;
    __bf16* wbT = (__bf16*)ws;
    char* zbuf = ws + WB_BYTES;
    __bf16* xb = (__bf16*)(ws + XB_OFF);

    const bool prex = ws_size >= (size_t)XB_OFF + (size_t)X_ELEMS * 2;

    prep_w_kernel<<<WB_ELEMS / 256, 256, 0, stream>>>(w, wbT);
    zero_kernel<<<1, 256, 0, stream>>>((float*)zbuf);

    if (prex) {
        prep_x_kernel<<<X_ELEMS / 8 / 256, 256, 0, stream>>>(x, xb);
        conv_mfma8_kernel<<<N_PIX / 256, 512, 0, stream>>>(
            (const char*)xb, (const char*)wbT, zbuf, out);
    } else {
        conv_fallback_kernel<<<N_PIX / 64, 256, 0, stream>>>(x, wbT, zbuf, out);
    }
}

// Round 4
// 319.405 us; speedup vs baseline: 1.0783x; 1.0783x over previous
//
#include <hip/hip_runtime.h>
#include <hip/hip_bf16.h>
#include <hip/hip_fp16.h>

typedef __bf16 bf16x8 __attribute__((ext_vector_type(8)));
typedef float  f32x4  __attribute__((ext_vector_type(4)));

#define C_H 56
#define C_W 56
#define C_C 256
#define C_F 256
#define C_B 64
#define N_PIX (C_B * C_H * C_W)          // 200704
#define WB_ELEMS (9 * C_C * C_F)         // 589824
#define WB_BYTES (WB_ELEMS * 2)          // 1179648
#define ZBUF_BYTES 1024
#define XB_OFF (WB_BYTES + ZBUF_BYTES)   // 1180672 (16B aligned)
#define X_ELEMS (N_PIX * C_C)            // 51380224

#define GLOAD_LDS16(g, l)                                                   \
    __builtin_amdgcn_global_load_lds(                                        \
        (const __attribute__((address_space(1))) void*)(g),                  \
        (__attribute__((address_space(3))) void*)(l), 16, 0, 0)

// ---- prep: binarize + transpose weights: w[s][c][f] fp32 -> wbT[s][f][c] bf16 ----
__global__ void prep_w_kernel(const float* __restrict__ w, __bf16* __restrict__ wbT) {
    int idx = blockIdx.x * 256 + threadIdx.x;       // 589824 total
    int f = idx & 255;
    int c = (idx >> 8) & 255;
    int s = idx >> 16;
    float wf = w[idx];
    float v = __half2float(__float2half(wf));       // fp16 round-trip
    float sgn = (v > 0.f) ? 1.f : ((v < 0.f) ? -1.f : 0.f);
    wbT[(s << 16) + (f << 8) + c] = (__bf16)sgn;
}

__global__ void zero_kernel(float* __restrict__ z) {
    z[threadIdx.x] = 0.f;   // 1KB zero page
}

__global__ void prep_x_kernel(const float* __restrict__ x, __bf16* __restrict__ xb) {
    int i = blockIdx.x * 256 + threadIdx.x;
    const f32x4* p = reinterpret_cast<const f32x4*>(x) + (size_t)i * 2;
    f32x4 a = p[0], b = p[1];
    bf16x8 o;
    o[0] = (__bf16)a[0]; o[1] = (__bf16)a[1]; o[2] = (__bf16)a[2]; o[3] = (__bf16)a[3];
    o[4] = (__bf16)b[0]; o[5] = (__bf16)b[1]; o[6] = (__bf16)b[2]; o[7] = (__bf16)b[3];
    reinterpret_cast<bf16x8*>(xb)[i] = o;
}

// ---- main conv: 256x256 tile, 8 waves (2Mx4N, 128x64/wave), BK=32 ----
// Register-pipelined: MFMA tile t from regs while ds_reading tile t+1 frags.
// 4 LDS bufs x 32KB; stage lookahead +3; counted vmcnt(4); 1 barrier/K-tile.
// Swizzle (64B rows): chunk' = chunk ^ ((row>>1)&3), applied source + read.
__global__ __launch_bounds__(512, 2) void conv_mfma8_kernel(
    const char* __restrict__ xbp,      // bf16 x [pixel][256c], 512B rows
    const char* __restrict__ wbp,      // bf16 wbT[s][f][c], 512B rows
    const char* __restrict__ zp,       // >=128B zeros, 16B aligned
    float* __restrict__ out) {

    __shared__ __align__(16) char sm[4][32768];   // [buf][A 16KB | B 16KB]

    // XCD-aware chunked swizzle: 784 blocks = 8 XCDs x 98
    const int nbid = (blockIdx.x & 7) * 98 + (blockIdx.x >> 3);
    const long m0 = (long)nbid * 256;

    const int tid  = threadIdx.x;
    const int lane = tid & 63;
    const int wave = tid >> 6;          // 0..7
    const int l15  = lane & 15;
    const int g4   = lane >> 4;         // 0..3
    const int wm   = wave >> 2;         // 0..1  (M half)
    const int wn   = wave & 3;          // 0..3  (N quarter)
    // read-side swizzled chunk: varies only with l15 (ai*16, wm*128 are mult of 4 rows)
    const int colr = ((g4 ^ ((l15 >> 1) & 3)) << 4);
    const int rdA = (wm * 128 + l15) * 64 + colr;           // A frag base (+ai*1024)
    const int rdB = 16384 + (wn * 64 + l15) * 64 + colr;    // B frag base (+bj*1024)

    // ---- staging precompute: thread covers rows r0, r0+128 in A and B, chunk tid&3 ----
    const int r0 = tid >> 2;                          // 0..127
    const int sw = ((tid & 3) ^ ((r0 >> 1) & 3)) << 4;   // inverse-swizzled source col
    const int p0 = (int)m0 + r0;
    const int p1 = p0 + 128;
    const int rem0 = p0 % 3136;
    const int rem1 = p1 % 3136;
    const int y0 = rem0 / 56, x0 = rem0 - (rem0 / 56) * 56;
    const int y1 = rem1 / 56, x1 = rem1 - (rem1 / 56) * 56;

    auto stage = [&](int kt) {
        int cc = (kt * 57) >> 9;             // kt/9 for kt<81
        int s  = kt - 9 * cc;
        int s3 = (s * 171) >> 9;             // s/3
        int dy = s3 - 1;
        int dx = s - 3 * s3 - 1;
        int doff = dy * 56 + dx;
        size_t cb = (size_t)(cc << 6) + sw;
        bool v0 = ((unsigned)(y0 + dy) < 56u) & ((unsigned)(x0 + dx) < 56u);
        bool v1 = ((unsigned)(y1 + dy) < 56u) & ((unsigned)(x1 + dx) < 56u);
        const char* a0 = v0 ? xbp + (size_t)(p0 + doff) * 512 + cb : zp + sw;
        const char* a1 = v1 ? xbp + (size_t)(p1 + doff) * 512 + cb : zp + sw;
        const char* b0 = wbp + (size_t)((s << 8) + r0) * 512 + cb;
        const char* b1 = wbp + (size_t)((s << 8) + r0 + 128) * 512 + cb;
        char* L = &sm[kt & 3][0];
        GLOAD_LDS16(a0, L + tid * 16);
        GLOAD_LDS16(a1, L + 8192 + tid * 16);
        GLOAD_LDS16(b0, L + 16384 + tid * 16);
        GLOAD_LDS16(b1, L + 24576 + tid * 16);
    };

    f32x4 acc[8][4];
#pragma unroll
    for (int i = 0; i < 8; ++i)
#pragma unroll
        for (int j = 0; j < 4; ++j)
            acc[i][j] = (f32x4){0.f, 0.f, 0.f, 0.f};

    bf16x8 Af[8], Bx[4], By[4];

    // body(t): barrier; [stage t+3]; MFMA tile t (regs) interleaved with
    // ds_read tile t+1 A-frags (in-place) ; then B-frags into Bn; lgkm(12).
    auto body = [&](int t, bf16x8 (&Bc)[4], bf16x8 (&Bn)[4], bool doStage, bool doPre) {
        __builtin_amdgcn_s_barrier();
        __builtin_amdgcn_sched_barrier(0);
        if (doStage) stage(t + 3);
        const char* L1 = &sm[(t + 1) & 3][0];
        const char* Ab = L1 + rdA;
        const char* Bb = L1 + rdB;
        __builtin_amdgcn_s_setprio(1);
#pragma unroll
        for (int ai = 0; ai < 8; ++ai) {
#pragma unroll
            for (int bj = 0; bj < 4; ++bj)
                acc[ai][bj] = __builtin_amdgcn_mfma_f32_16x16x32_bf16(
                    Af[ai], Bc[bj], acc[ai][bj], 0, 0, 0);
            if (doPre)
                Af[ai] = *reinterpret_cast<const bf16x8*>(Ab + ai * 1024);
        }
        __builtin_amdgcn_s_setprio(0);
        if (doPre) {
#pragma unroll
            for (int bj = 0; bj < 4; ++bj)
                Bn[bj] = *reinterpret_cast<const bf16x8*>(Bb + bj * 1024);
            asm volatile("s_waitcnt lgkmcnt(12)" ::: "memory");
            __builtin_amdgcn_sched_barrier(0);
        }
    };

    // ---- prologue: 3 tiles in flight; load tile-0 fragments ----
    stage(0); stage(1); stage(2);
    asm volatile("s_waitcnt vmcnt(8)" ::: "memory");   // own tile-0 loads landed
    __builtin_amdgcn_s_barrier();                      // everyone's landed
    __builtin_amdgcn_sched_barrier(0);
    {
        const char* L0 = &sm[0][0];
#pragma unroll
        for (int ai = 0; ai < 8; ++ai)
            Af[ai] = *reinterpret_cast<const bf16x8*>(L0 + rdA + ai * 1024);
#pragma unroll
        for (int bj = 0; bj < 4; ++bj)
            Bx[bj] = *reinterpret_cast<const bf16x8*>(L0 + rdB + bj * 1024);
    }
    asm volatile("s_waitcnt lgkmcnt(0)" ::: "memory");
    __builtin_amdgcn_sched_barrier(0);

    // ---- main loop: t = 0..67, stage t+3, vmcnt(4) = 2 stages outstanding ----
    for (int tt = 0; tt < 68; tt += 2) {
        asm volatile("s_waitcnt vmcnt(4)" ::: "memory");
        body(tt, Bx, By, true, true);
        asm volatile("s_waitcnt vmcnt(4)" ::: "memory");
        body(tt + 1, By, Bx, true, true);
    }
    // ---- tail: t = 68 (stage 71), 69, 70 (vmcnt 0), 71 (MFMA only) ----
    asm volatile("s_waitcnt vmcnt(4)" ::: "memory");
    body(68, Bx, By, true, true);
    asm volatile("s_waitcnt vmcnt(4)" ::: "memory");
    body(69, By, Bx, false, true);
    asm volatile("s_waitcnt vmcnt(0)" ::: "memory");
    body(70, Bx, By, false, true);
    body(71, By, Bx, false, false);

    // ---- epilogue: D col(f)=lane&15, row(pixel)=(lane>>4)*4+j ----
#pragma unroll
    for (int ai = 0; ai < 8; ++ai) {
#pragma unroll
        for (int j = 0; j < 4; ++j) {
            long row = m0 + wm * 128 + ai * 16 + g4 * 4 + j;
            float* op = out + row * C_F + wn * 64 + l15;
#pragma unroll
            for (int bj = 0; bj < 4; ++bj)
                op[bj * 16] = acc[ai][bj][j];
        }
    }
}

// ---- fallback (small ws): direct-from-global version ----
__global__ __launch_bounds__(256) void conv_fallback_kernel(
    const float* __restrict__ xf,
    const __bf16* __restrict__ wbT, const char* __restrict__ zbuf,
    float* __restrict__ out) {

    const int lane = threadIdx.x & 63;
    const int wave = threadIdx.x >> 6;
    const int l15  = lane & 15;
    const int g    = lane >> 4;
    const int goff = g * 8;
    const long m0  = (long)blockIdx.x * 64;
    const int fbase = wave * 64;

    int ry[4], rx[4];
    long rbase[4];
#pragma unroll
    for (int ai = 0; ai < 4; ++ai) {
        int rr = (int)m0 + ai * 16 + l15;
        int b = rr / 3136;
        int rem = rr - b * 3136;
        int yy2 = rem / 56;
        ry[ai] = yy2;
        rx[ai] = rem - yy2 * 56;
        rbase[ai] = (long)rr * C_C;
    }

    f32x4 acc[4][4];
#pragma unroll
    for (int i = 0; i < 4; ++i)
#pragma unroll
        for (int j = 0; j < 4; ++j)
            acc[i][j] = (f32x4){0.f, 0.f, 0.f, 0.f};

    for (int s = 0; s < 9; ++s) {
        const int dy = s / 3 - 1;
        const int dx = (s - (s / 3) * 3) - 1;
        const float* af[4];
#pragma unroll
        for (int ai = 0; ai < 4; ++ai) {
            bool v = ((unsigned)(ry[ai] + dy) < 56u) & ((unsigned)(rx[ai] + dx) < 56u);
            long off = rbase[ai] + (long)(dy * C_W + dx) * C_C + goff;
            af[ai] = v ? (xf + off) : ((const float*)zbuf + goff);
        }
        const __bf16* bp = wbT + ((size_t)(s * 256 + fbase + l15)) * C_C + goff;

#pragma unroll
        for (int cc = 0; cc < 8; ++cc) {
            const int c0 = cc * 32;
            bf16x8 A[4], Bf[4];
#pragma unroll
            for (int ai = 0; ai < 4; ++ai) {
                const f32x4* p = reinterpret_cast<const f32x4*>(af[ai] + c0);
                f32x4 u = p[0], w2 = p[1];
                bf16x8 t;
                t[0] = (__bf16)u[0]; t[1] = (__bf16)u[1]; t[2] = (__bf16)u[2]; t[3] = (__bf16)u[3];
                t[4] = (__bf16)w2[0]; t[5] = (__bf16)w2[1]; t[6] = (__bf16)w2[2]; t[7] = (__bf16)w2[3];
                A[ai] = t;
            }
#pragma unroll
            for (int bj = 0; bj < 4; ++bj)
                Bf[bj] = *reinterpret_cast<const bf16x8*>(bp + bj * 16 * C_C + c0);
#pragma unroll
            for (int ai = 0; ai < 4; ++ai)
#pragma unroll
                for (int bj = 0; bj < 4; ++bj)
                    acc[ai][bj] = __builtin_amdgcn_mfma_f32_16x16x32_bf16(A[ai], Bf[bj], acc[ai][bj], 0, 0, 0);
        }
    }

#pragma unroll
    for (int ai = 0; ai < 4; ++ai) {
#pragma unroll
        for (int j = 0; j < 4; ++j) {
            long row = m0 + ai * 16 + g * 4 + j;
            float* op = out + row * C_F + fbase + l15;
#pragma unroll
            for (int bj = 0; bj < 4; ++bj)
                op[bj * 16] = acc[ai][bj][j];
        }
    }
}

extern "C" void kernel_launch(void* const* d_in, const int* in_sizes, int n_in,
                              void* d_out, int out_size, void* d_ws, size_t ws_size,
                              hipStream_t stream) {
    const float* x = (const float*)d_in[0];
    const float* w = (const float*)d_in[1];
    float* out = (float*)d_out;

    char* ws = (char*)d_ws;
    __bf16* wbT = (__bf16*)ws;
    char* zbuf = ws + WB_BYTES;
    __bf16* xb = (__bf16*)(ws + XB_OFF);

    const bool prex = ws_size >= (size_t)XB_OFF + (size_t)X_ELEMS * 2;

    prep_w_kernel<<<WB_ELEMS / 256, 256, 0, stream>>>(w, wbT);
    zero_kernel<<<1, 256, 0, stream>>>((float*)zbuf);

    if (prex) {
        prep_x_kernel<<<X_ELEMS / 8 / 256, 256, 0, stream>>>(x, xb);
        conv_mfma8_kernel<<<N_PIX / 256, 512, 0, stream>>>(
            (const char*)xb, (const char*)wbT, zbuf, out);
    } else {
        conv_fallback_kernel<<<N_PIX / 64, 256, 0, stream>>>(x, wbT, zbuf, out);
    }
}